// Round 1
// 254.609 us; speedup vs baseline: 1.0430x; 1.0430x over previous
//
#include <hip/hip_runtime.h>
#include <hip/hip_fp16.h>

// CapsNet dynamic routing, B=256, P=2048, C=10, OUT=16, IN=8, 3 iters.
// uhat layout: [p][h][b][80co] fp16 (h = c-half). Dense unit per (p,h) is
// 256*160B = 40KB contiguous.
// k_uhat (R7): inverted mapping. Stage u[:,p,:] (12KB, pad-12 so b128-aligned,
//   8-bank spread) and W[p] (5.4KB, 68-float chunk skew -> <=2-way conflicts,
//   broadcast reads) in LDS; each thread computes output chunks in FLAT store
//   order f = tid + 256*k, so every wave store is a dense 1KB dwordx4 burst.
//   No 45KB restage slab (R6 was 3 blocks/CU LDS-limited + 336MB LDS traffic);
//   LDS now 17.7KB -> 4-8 blocks/CU, kernel becomes store-BW-bound.
// k_route: R6 verbatim (TPB=512 - the only TPB where the VGPR budget
//   behaves; 1024 pinned 64 regs twice -> spill).

#define Bn 256
#define Pn 2048
#define Cn 10
#define On 16
#define In 8
#define ROW 160            // Cn*On
#define TPB 512
#define PAIRS (TPB / 2)    // 256
#define ITERS (Pn / PAIRS) // 8
#define NW (TPB / 64)      // 8 waves
#define CH 5               // c's per half-thread
#define HROW 80            // CH*On

typedef _Float16 h2f __attribute__((ext_vector_type(2)));
union RowU { float4 f[2]; h2f hh2[8]; __half hh[16]; };

// ---------------- k_uhat ----------------
// grid = Pn, TPB = 256. Thread t stages u row b=t; compute loop is store-ordered.
__global__ __launch_bounds__(256) void k_uhat(const float* __restrict__ u,
                                              const float* __restrict__ W,
                                              __half* __restrict__ uhat) {
  __shared__ float uL[Bn * 12];   // u[b][i], stride 12 floats: 16B-aligned, 8-bank spread; 12288 B
  __shared__ float wL[20 * 68];   // (h*10+chunk)*68 + cell*8 + i; skew 68 -> chunk bank-offsets 4c mod 32; 5440 B
  const int p = blockIdx.x;
  const int t = threadIdx.x;

  // stage u[:, p, :] - thread t loads b=t's 8 floats (two f4, 64KB lane stride; tiny volume)
  {
    const float4* up = reinterpret_cast<const float4*>(u + ((size_t)t * Pn + p) * In);
    float4 a0 = up[0], a1 = up[1];
    float4* d = reinterpret_cast<float4*>(&uL[t * 12]);
    d[0] = a0;
    d[1] = a1;
  }
  // stage W[p] (1280 floats) coalesced, scattered into skewed layout
  {
    const float4* wp = reinterpret_cast<const float4*>(W + (size_t)p * (Cn * On * In));
    float4 v0 = wp[t];
    const int lin = 4 * t;
    float* d = &wL[(lin >> 6) * 68 + (lin & 63)];
    d[0] = v0.x; d[1] = v0.y; d[2] = v0.z; d[3] = v0.w;
    if (t < 64) {
      float4 v1 = wp[256 + t];
      const int lin1 = 1024 + 4 * t;
      float* d1 = &wL[(lin1 >> 6) * 68 + (lin1 & 63)];
      d1[0] = v1.x; d1[1] = v1.y; d1[2] = v1.z; d1[3] = v1.w;
    }
  }
  __syncthreads();

#pragma unroll
  for (int h = 0; h < 2; ++h) {
    __half* gh = uhat + (size_t)(p * 2 + h) * (Bn * HROW);
    const float* wh = &wL[h * 10 * 68];
#pragma unroll 5
    for (int kk = 0; kk < 10; ++kk) {
      const int fh = t + 256 * kk;   // flat chunk index: fh = b*10 + chunk
      const int b = fh / 10;         // magic-mul
      const int chunk = fh - b * 10;
      const float4 ua = *reinterpret_cast<const float4*>(&uL[b * 12]);
      const float4 ubv = *reinterpret_cast<const float4*>(&uL[b * 12 + 4]);
      const float uu[8] = {ua.x, ua.y, ua.z, ua.w, ubv.x, ubv.y, ubv.z, ubv.w};
      const float* wc = wh + chunk * 68;  // 64 floats: 8 cells x 8 i (broadcast across lanes)
      union { float4 f; __half2 h2[4]; } ov;
#pragma unroll
      for (int j = 0; j < 4; ++j) {
        const float* w0 = wc + j * 16;  // cells 2j, 2j+1
        float d0 = w0[0] * uu[0];
        float d1 = w0[8] * uu[0];
#pragma unroll
        for (int i = 1; i < 8; ++i) {
          d0 = __builtin_fmaf(w0[i], uu[i], d0);
          d1 = __builtin_fmaf(w0[8 + i], uu[i], d1);
        }
        ov.h2[j] = __floats2half2_rn(d0, d1);
      }
      // lanes cover consecutive fh -> dense 1KB wave store
      *reinterpret_cast<float4*>(gh + (size_t)fh * 8) = ov.f;
    }
  }
}

// ---------------- k_route ----------------
__device__ __forceinline__ void reduce_squash(float (&acc)[CH][On], float scale,
                                              int tid, int lane, int w, int h,
                                              float (*s_red)[ROW], float* s_lds,
                                              float* v_lds, __half2 (*v_h2)[8]) {
#pragma unroll
  for (int k = 0; k < HROW; ++k) {
    float x = acc[k >> 4][k & 15];
#pragma unroll
    for (int off = 2; off <= 32; off <<= 1) x += __shfl_xor(x, off, 64);
    if ((lane >> 1) == (k & 31)) s_red[w][h * HROW + k] = x;
  }
  __syncthreads();
  if (tid < ROW) {
    float tsum = 0.f;
#pragma unroll
    for (int ww = 0; ww < NW; ++ww) tsum += s_red[ww][tid];
    s_lds[tid] = scale * tsum;
  }
  __syncthreads();
  if (tid < Cn) {
    float sq = 0.f;
#pragma unroll
    for (int o = 0; o < On; ++o) {
      float x = s_lds[tid * On + o];
      sq += x * x;
    }
    float sc = (sq / (1.f + sq)) / sqrtf(sq + 1e-9f);
#pragma unroll
    for (int o = 0; o < On; ++o) v_lds[tid * On + o] = sc * s_lds[tid * On + o];
#pragma unroll
    for (int o2 = 0; o2 < 8; ++o2)
      v_h2[tid][o2] = __floats2half2_rn(v_lds[tid * On + 2 * o2],
                                        v_lds[tid * On + 2 * o2 + 1]);
  }
  __syncthreads();
}

__global__ __launch_bounds__(TPB, 2) void k_route(const __half* __restrict__ uhat,
                                                  float* __restrict__ out) {
  __shared__ __half lg_lds[Pn][2][CH]; // 40960 B
  __shared__ float s_red[NW][ROW];     // 5120 B
  __shared__ float s_lds[ROW];
  __shared__ float v_lds[ROW];
  __shared__ __half2 v_h2[Cn][8];
  // swizzle: adjacent-b blocks land on one XCD for L2 line sharing
  const int x = blockIdx.x;
  const int b = (x & 31) * 8 + (x >> 5);
  const int tid = threadIdx.x;
  const int lane = tid & 63;
  const int w = tid >> 6;
  const int h = tid & 1;   // c-half this thread owns
  const int pr = tid >> 1; // pair index in [0,256)

  float acc[CH][On];

  // ---- PASS 1: weights uniform 0.1 ----
#pragma unroll
  for (int kc = 0; kc < CH; ++kc)
#pragma unroll
    for (int o = 0; o < On; ++o) acc[kc][o] = 0.f;
  for (int it = 0; it < ITERS; ++it) {
    const int p = pr + PAIRS * it;
    const __half* row = uhat + (((size_t)p * 2 + h) * Bn + b) * HROW;
#pragma unroll
    for (int kc = 0; kc < CH; ++kc) {
      RowU q;
      q.f[0] = *reinterpret_cast<const float4*>(row + kc * 16);
      q.f[1] = *reinterpret_cast<const float4*>(row + kc * 16 + 8);
#pragma unroll
      for (int o = 0; o < On; ++o) acc[kc][o] += __half2float(q.hh[o]);
    }
  }
  reduce_squash(acc, 0.1f, tid, lane, w, h, s_red, s_lds, v_lds, v_h2);

  // ---- PASSES 2,3 (b-update folded into softmax) ----
  for (int pass = 0; pass < 2; ++pass) {
#pragma unroll
    for (int kc = 0; kc < CH; ++kc)
#pragma unroll
      for (int o = 0; o < On; ++o) acc[kc][o] = 0.f;
    for (int it = 0; it < ITERS; ++it) {
      const int p = pr + PAIRS * it;
      const __half* row = uhat + (((size_t)p * 2 + h) * Bn + b) * HROW;
      RowU q[CH]; // kept live through dot -> softmax -> acc (no reload)
      float lg[CH];
#pragma unroll
      for (int kc = 0; kc < CH; ++kc) {
        q[kc].f[0] = *reinterpret_cast<const float4*>(row + kc * 16);
        q[kc].f[1] = *reinterpret_cast<const float4*>(row + kc * 16 + 8);
        float d = 0.f;
#pragma unroll
        for (int o2 = 0; o2 < 8; ++o2) {
          h2f vv = *reinterpret_cast<const h2f*>(&v_h2[h * CH + kc][o2]); // uniform: LDS broadcast
          d = __builtin_amdgcn_fdot2(q[kc].hh2[o2], vv, d, false);
        }
        lg[kc] = (pass == 0) ? d : (d + __half2float(lg_lds[p][h][kc]));
      }
      if (pass == 0) {
#pragma unroll
        for (int kc = 0; kc < CH; ++kc) lg_lds[p][h][kc] = __float2half(lg[kc]);
      }
      // softmax across both halves via 2 shuffles
      float m = lg[0];
#pragma unroll
      for (int kc = 1; kc < CH; ++kc) m = fmaxf(m, lg[kc]);
      m = fmaxf(m, __shfl_xor(m, 1, 64));
      float e[CH], ssum = 0.f;
#pragma unroll
      for (int kc = 0; kc < CH; ++kc) {
        e[kc] = __expf(lg[kc] - m);
        ssum += e[kc];
      }
      ssum += __shfl_xor(ssum, 1, 64);
      const float inv = 1.f / ssum;
#pragma unroll
      for (int kc = 0; kc < CH; ++kc) {
        const float cv = e[kc] * inv;
#pragma unroll
        for (int o = 0; o < On; ++o)
          acc[kc][o] = __builtin_fmaf(cv, __half2float(q[kc].hh[o]), acc[kc][o]);
      }
    }
    reduce_squash(acc, 1.0f, tid, lane, w, h, s_red, s_lds, v_lds, v_h2);
  }

  if (tid < ROW) out[(size_t)b * ROW + tid] = v_lds[tid];
}

extern "C" void kernel_launch(void* const* d_in, const int* in_sizes, int n_in,
                              void* d_out, int out_size, void* d_ws, size_t ws_size,
                              hipStream_t stream) {
  (void)in_sizes; (void)n_in; (void)out_size;
  const float* u = (const float*)d_in[0];
  const float* W = (const float*)d_in[1];
  float* out = (float*)d_out;
  __half* uhat = (__half*)d_ws;
  const size_t need = (size_t)Bn * Pn * Cn * On * sizeof(__half);
  if (ws_size < need) return; // needs ~168 MB scratch
  k_uhat<<<Pn, 256, 0, stream>>>(u, W, uhat);
  k_route<<<Bn, TPB, 0, stream>>>(uhat, out);
}